// Round 1
// baseline (418.605 us; speedup 1.0000x reference)
//
#include <hip/hip_runtime.h>

// GestureRNN: 2-layer ReLU RNN, B=4096, T=512, IN=10, H=32, NCLS=9.
// Layout: lane j (0..31) owns hidden unit j; 2 batch elements per wave
// (g = lane>>5); single-wave blocks (64 thr) so __syncthreads() is
// wave-local (s_barrier elided, just lgkmcnt ordering). Weight rows live
// in VGPRs (~106 floats/lane); h1/h2 round-trip through LDS as float4
// broadcast reads (2-way bank aliasing = free).

constexpr int T_   = 512;
constexpr int IN_  = 10;
constexpr int H_   = 32;
constexpr int NC_  = 9;

__global__ __launch_bounds__(64, 1) void gesture_rnn_kernel(
    const float* __restrict__ x,      // [B, T, IN]
    const float* __restrict__ W_ih0,  // [H, IN]
    const float* __restrict__ W_hh0,  // [H, H]
    const float* __restrict__ b_ih0,  // [H]
    const float* __restrict__ b_hh0,  // [H]
    const float* __restrict__ W_ih1,  // [H, H]
    const float* __restrict__ W_hh1,  // [H, H]
    const float* __restrict__ b_ih1,  // [H]
    const float* __restrict__ b_hh1,  // [H]
    const float* __restrict__ W_fc,   // [NC, H]
    const float* __restrict__ b_fc,   // [NC]
    float* __restrict__ out)          // [B, NC]
{
    const int lane = threadIdx.x;     // 0..63
    const int g    = lane >> 5;       // batch sub-group within wave: 0..1
    const int j    = lane & 31;       // hidden unit index
    const long b   = (long)blockIdx.x * 2 + g;

    // ---- register-cached weight rows for hidden unit j ----
    float wih0[IN_];
    float whh0[H_], wih1[H_], whh1[H_];
#pragma unroll
    for (int i = 0; i < IN_; ++i) wih0[i] = W_ih0[j * IN_ + i];
#pragma unroll
    for (int k = 0; k < H_; ++k) {
        whh0[k] = W_hh0[j * H_ + k];
        wih1[k] = W_ih1[j * H_ + k];
        whh1[k] = W_hh1[j * H_ + k];
    }
    const float bias0 = b_ih0[j] + b_hh0[j];
    const float bias1 = b_ih1[j] + b_hh1[j];

    __shared__ __align__(16) float h1s[2][H_];
    __shared__ __align__(16) float h2s[2][H_];
    h1s[g][j] = 0.0f;
    h2s[g][j] = 0.0f;
    __syncthreads();

    const float* xb = x + (size_t)b * T_ * IN_;

    // preload x[t=0]
    float xv[IN_];
#pragma unroll
    for (int i = 0; i < IN_; i += 2) {
        float2 v = *(const float2*)(xb + i);
        xv[i] = v.x; xv[i + 1] = v.y;
    }

#pragma unroll 1
    for (int t = 0; t < T_; ++t) {
        // x-projection for this step (consumes xv)
        float a1x = bias0;
#pragma unroll
        for (int i = 0; i < IN_; ++i) a1x = fmaf(wih0[i], xv[i], a1x);

        // prefetch next step's x (latency hidden behind h-compute)
        if (t + 1 < T_) {
            const float* xn = xb + (size_t)(t + 1) * IN_;
#pragma unroll
            for (int i = 0; i < IN_; i += 2) {
                float2 v = *(const float2*)(xn + i);
                xv[i] = v.x; xv[i + 1] = v.y;
            }
        }

        // a1 += W_hh0[j,:] . h1_old ; a2 partial = W_hh1[j,:] . h2_old
        float a1h0 = 0.f, a1h1 = 0.f, a2o0 = 0.f, a2o1 = 0.f;
#pragma unroll
        for (int k = 0; k < H_; k += 8) {
            float4 h1a = *(const float4*)&h1s[g][k];
            float4 h1b = *(const float4*)&h1s[g][k + 4];
            float4 h2a = *(const float4*)&h2s[g][k];
            float4 h2b = *(const float4*)&h2s[g][k + 4];
            a1h0 = fmaf(whh0[k    ], h1a.x, a1h0);
            a1h0 = fmaf(whh0[k + 1], h1a.y, a1h0);
            a1h0 = fmaf(whh0[k + 2], h1a.z, a1h0);
            a1h0 = fmaf(whh0[k + 3], h1a.w, a1h0);
            a1h1 = fmaf(whh0[k + 4], h1b.x, a1h1);
            a1h1 = fmaf(whh0[k + 5], h1b.y, a1h1);
            a1h1 = fmaf(whh0[k + 6], h1b.z, a1h1);
            a1h1 = fmaf(whh0[k + 7], h1b.w, a1h1);
            a2o0 = fmaf(whh1[k    ], h2a.x, a2o0);
            a2o0 = fmaf(whh1[k + 1], h2a.y, a2o0);
            a2o0 = fmaf(whh1[k + 2], h2a.z, a2o0);
            a2o0 = fmaf(whh1[k + 3], h2a.w, a2o0);
            a2o1 = fmaf(whh1[k + 4], h2b.x, a2o1);
            a2o1 = fmaf(whh1[k + 5], h2b.y, a2o1);
            a2o1 = fmaf(whh1[k + 6], h2b.z, a2o1);
            a2o1 = fmaf(whh1[k + 7], h2b.w, a2o1);
        }
        const float a1 = a1x + a1h0 + a1h1;

        __syncthreads();                 // all reads of h1_old/h2_old done
        h1s[g][j] = fmaxf(a1, 0.0f);     // publish h1_new
        __syncthreads();                 // h1_new visible

        // a2 += W_ih1[j,:] . h1_new
        float a2n0 = bias1, a2n1 = 0.f;
#pragma unroll
        for (int k = 0; k < H_; k += 8) {
            float4 h1a = *(const float4*)&h1s[g][k];
            float4 h1b = *(const float4*)&h1s[g][k + 4];
            a2n0 = fmaf(wih1[k    ], h1a.x, a2n0);
            a2n0 = fmaf(wih1[k + 1], h1a.y, a2n0);
            a2n0 = fmaf(wih1[k + 2], h1a.z, a2n0);
            a2n0 = fmaf(wih1[k + 3], h1a.w, a2n0);
            a2n1 = fmaf(wih1[k + 4], h1b.x, a2n1);
            a2n1 = fmaf(wih1[k + 5], h1b.y, a2n1);
            a2n1 = fmaf(wih1[k + 6], h1b.z, a2n1);
            a2n1 = fmaf(wih1[k + 7], h1b.w, a2n1);
        }
        const float a2 = a2n0 + a2n1 + a2o0 + a2o1;
        h2s[g][j] = fmaxf(a2, 0.0f);     // h2_old reads all happened pre-B1
        __syncthreads();                 // h2_new visible for next iteration
    }

    // ---- epilogue: out[b, c] = W_fc[c,:] . h2_last + b_fc[c] ----
    if (j < NC_) {
        float acc = b_fc[j];
#pragma unroll
        for (int k = 0; k < H_; ++k)
            acc = fmaf(W_fc[j * H_ + k], h2s[g][k], acc);
        out[b * NC_ + j] = acc;
    }
}

extern "C" void kernel_launch(void* const* d_in, const int* in_sizes, int n_in,
                              void* d_out, int out_size, void* d_ws, size_t ws_size,
                              hipStream_t stream) {
    const float* x     = (const float*)d_in[0];
    const float* W_ih0 = (const float*)d_in[1];
    const float* W_hh0 = (const float*)d_in[2];
    const float* b_ih0 = (const float*)d_in[3];
    const float* b_hh0 = (const float*)d_in[4];
    const float* W_ih1 = (const float*)d_in[5];
    const float* W_hh1 = (const float*)d_in[6];
    const float* b_ih1 = (const float*)d_in[7];
    const float* b_hh1 = (const float*)d_in[8];
    const float* W_fc  = (const float*)d_in[9];
    const float* b_fc  = (const float*)d_in[10];
    float* out = (float*)d_out;

    const int B = 4096;
    gesture_rnn_kernel<<<dim3(B / 2), dim3(64), 0, stream>>>(
        x, W_ih0, W_hh0, b_ih0, b_hh0, W_ih1, W_hh1, b_ih1, b_hh1,
        W_fc, b_fc, out);
}